// Round 5
// baseline (685.649 us; speedup 1.0000x reference)
//
#include <hip/hip_runtime.h>

// GCN 2-layer. Edges partitioned once into 391 dst-buckets (256 nodes each);
// each layer aggregates per-bucket in LDS via ds_add_f32 (max MLP on the
// random h reads), with norms / bias / relu / W2-GEMM fused in the epilogue.
// No CSR, no global fp32 atomics, no per-row serial walks.

#define NB   391      // ceil(100000/256); bucket = node >> 8
#define CAPB 5504     // per-bucket edge capacity (avg 4092, +22 sigma)
#define EPB  4096     // edges per partition block (16/thread)

// --- pass 1: partition edges by dst-bucket {src | dl<<20, w}; src ids by
//     src-bucket (uchar local id) for the out-degree histogram. ---
__global__ void partition_kernel(const int* __restrict__ src, const int* __restrict__ dst,
                                 const float* __restrict__ ew,
                                 int* __restrict__ g_cur_d, int* __restrict__ g_cur_s,
                                 int2* __restrict__ pack, unsigned char* __restrict__ sp,
                                 int m) {
    __shared__ int hist_d[NB], hist_s[NB];
    __shared__ int cur_d[NB], cur_s[NB];
    int t = threadIdx.x;
    for (int i = t; i < NB; i += 256) { hist_d[i] = 0; hist_s[i] = 0; }
    __syncthreads();
    int base_e = blockIdx.x * EPB;
    int es[16], ed[16]; float wv[16];
#pragma unroll
    for (int k = 0; k < 16; k++) {
        int e = base_e + k * 256 + t;
        if (e < m) { es[k] = src[e]; ed[k] = dst[e]; wv[k] = ew[e]; }
        else ed[k] = -1;
    }
#pragma unroll
    for (int k = 0; k < 16; k++) {
        if (ed[k] >= 0) {
            atomicAdd(&hist_d[ed[k] >> 8], 1);
            atomicAdd(&hist_s[es[k] >> 8], 1);
        }
    }
    __syncthreads();
    for (int i = t; i < NB; i += 256) {
        int c = hist_d[i];
        cur_d[i] = i * CAPB + (c ? atomicAdd(&g_cur_d[i], c) : 0);
        c = hist_s[i];
        cur_s[i] = i * CAPB + (c ? atomicAdd(&g_cur_s[i], c) : 0);
    }
    __syncthreads();
#pragma unroll
    for (int k = 0; k < 16; k++) {
        if (ed[k] >= 0) {
            int d = ed[k], s = es[k];
            int bb = d >> 8;
            int pos = atomicAdd(&cur_d[bb], 1);
            if (pos < (bb + 1) * CAPB)
                pack[pos] = make_int2(s | ((d & 255) << 20), __float_as_int(wv[k]));
            int sb = s >> 8;
            int ps = atomicAdd(&cur_s[sb], 1);
            if (ps < (sb + 1) * CAPB)
                sp[ps] = (unsigned char)(s & 255);
        }
    }
}

// --- per src-bucket: out-degree in LDS -> norm_src (dense write) ---
__global__ void srcnorm_kernel(const unsigned char* __restrict__ sp,
                               const int* __restrict__ g_cur_s,
                               float* __restrict__ norm_src, int n) {
    __shared__ int cnt[256];
    int t = threadIdx.x, b = blockIdx.x;
    cnt[t] = 0;
    __syncthreads();
    int count = g_cur_s[b]; if (count > CAPB) count = CAPB;
    const unsigned char* p = sp + (size_t)b * CAPB;
    for (int e = t; e < count; e += 256) atomicAdd(&cnt[p[e]], 1);
    __syncthreads();
    int node = b * 256 + t;
    if (node < n) {
        int c = cnt[t];
        norm_src[node] = rsqrtf((float)(c > 1 ? c : 1));
    }
}

// --- h1[n,32] = (feat * norm_src) @ W1 ---
__global__ void transform1_kernel(const float* __restrict__ feat,
                                  const float* __restrict__ norm_src,
                                  const float* __restrict__ W1,
                                  float* __restrict__ h1, int n) {
    __shared__ float sW[32 * 32];
    __shared__ float sF[8][32];
    int t = threadIdx.x;
    for (int i = t; i < 32 * 32; i += 256) sW[i] = W1[i];
    int node0 = blockIdx.x * 8;
    int local = t >> 5, col = t & 31;
    int node = node0 + local;
    float f = 0.0f;
    if (node < n) f = feat[node * 32 + col] * norm_src[node];
    sF[local][col] = f;
    __syncthreads();
    if (node < n) {
        float acc = 0.0f;
#pragma unroll
        for (int k = 0; k < 32; k++) acc += sF[local][k] * sW[k * 32 + col];
        h1[node * 32 + col] = acc;
    }
}

// --- layer-1 aggregate per dst-bucket + fused norm/relu/W2 -> h2, norm_dst ---
__global__ void agg1_kernel(const float* __restrict__ h1, const int2* __restrict__ pack,
                            const int* __restrict__ g_cur_d,
                            const float* __restrict__ norm_src,
                            const float* __restrict__ W2, const float* __restrict__ b1,
                            float* __restrict__ h2, float* __restrict__ norm_dst, int n) {
    __shared__ float agg[256 * 33];   // stride 33: conflict-free
    __shared__ int cnt[256];
    __shared__ float sW2[32 * 16];
    __shared__ float sB1[32];
    int t = threadIdx.x, b = blockIdx.x;
    for (int i = t; i < 256 * 33; i += 256) agg[i] = 0.0f;
    cnt[t] = 0;
    for (int i = t; i < 512; i += 256) sW2[i] = W2[i];
    if (t < 32) sB1[t] = b1[t];
    __syncthreads();
    int count = g_cur_d[b]; if (count > CAPB) count = CAPB;
    const int2* pk = pack + (size_t)b * CAPB;
    int d = t & 31;
    int el = t >> 5;                  // edge lane 0..7
    int full = count & ~31;
    for (int e0 = 0; e0 < full; e0 += 32) {   // 32 edges/iter, 8 loads in flight
        int2 p0 = pk[e0 + el];
        int2 p1 = pk[e0 + 8 + el];
        int2 p2 = pk[e0 + 16 + el];
        int2 p3 = pk[e0 + 24 + el];
        float v0 = h1[(size_t)(p0.x & 0xFFFFF) * 32 + d] * __int_as_float(p0.y);
        float v1 = h1[(size_t)(p1.x & 0xFFFFF) * 32 + d] * __int_as_float(p1.y);
        float v2 = h1[(size_t)(p2.x & 0xFFFFF) * 32 + d] * __int_as_float(p2.y);
        float v3 = h1[(size_t)(p3.x & 0xFFFFF) * 32 + d] * __int_as_float(p3.y);
        atomicAdd(&agg[(p0.x >> 20) * 33 + d], v0);
        atomicAdd(&agg[(p1.x >> 20) * 33 + d], v1);
        atomicAdd(&agg[(p2.x >> 20) * 33 + d], v2);
        atomicAdd(&agg[(p3.x >> 20) * 33 + d], v3);
        if (d == 0) {
            atomicAdd(&cnt[p0.x >> 20], 1);
            atomicAdd(&cnt[p1.x >> 20], 1);
            atomicAdd(&cnt[p2.x >> 20], 1);
            atomicAdd(&cnt[p3.x >> 20], 1);
        }
    }
    for (int e0 = full; e0 < count; e0 += 8) {
        int e = e0 + el;
        if (e < count) {
            int2 p = pk[e];
            float v = h1[(size_t)(p.x & 0xFFFFF) * 32 + d] * __int_as_float(p.y);
            atomicAdd(&agg[(p.x >> 20) * 33 + d], v);
            if (d == 0) atomicAdd(&cnt[p.x >> 20], 1);
        }
    }
    __syncthreads();
    // x = relu(agg*norm_dst + b1) * norm_src, in place
    int node0 = b * 256;
    for (int o = t; o < 256 * 32; o += 256) {
        int i = o >> 5, k = o & 31;
        int node = node0 + i;
        float ns = (node < n) ? norm_src[node] : 0.0f;
        int c = cnt[i];
        float nd = rsqrtf((float)(c > 1 ? c : 1));
        float x = agg[i * 33 + k] * nd + sB1[k];
        agg[i * 33 + k] = fmaxf(x, 0.0f) * ns;
    }
    {
        int node = node0 + t;
        if (node < n) {
            int c = cnt[t];
            norm_dst[node] = rsqrtf((float)(c > 1 ? c : 1));
        }
    }
    __syncthreads();
    // h2[256,16] = x[256,32] @ W2[32,16]
    for (int o = t; o < 256 * 16; o += 256) {
        int i = o >> 4, c = o & 15;
        float acc = 0.0f;
#pragma unroll
        for (int k = 0; k < 32; k++) acc += agg[i * 33 + k] * sW2[k * 16 + c];
        int node = node0 + i;
        if (node < n) h2[(size_t)node * 16 + c] = acc;
    }
}

// --- layer-2 aggregate per dst-bucket + fused norm/bias -> out ---
__global__ void agg2_kernel(const float* __restrict__ h2, const int2* __restrict__ pack,
                            const int* __restrict__ g_cur_d,
                            const float* __restrict__ norm_dst, const float* __restrict__ b2,
                            float* __restrict__ out, int n) {
    __shared__ float agg[256 * 17];   // stride 17
    __shared__ float sB2[16];
    int t = threadIdx.x, b = blockIdx.x;
    for (int i = t; i < 256 * 17; i += 256) agg[i] = 0.0f;
    if (t < 16) sB2[t] = b2[t];
    __syncthreads();
    int count = g_cur_d[b]; if (count > CAPB) count = CAPB;
    const int2* pk = pack + (size_t)b * CAPB;
    int d = t & 15;
    int el = t >> 4;                  // edge lane 0..15
    int full = count & ~63;
    for (int e0 = 0; e0 < full; e0 += 64) {   // 64 edges/iter
        int2 p0 = pk[e0 + el];
        int2 p1 = pk[e0 + 16 + el];
        int2 p2 = pk[e0 + 32 + el];
        int2 p3 = pk[e0 + 48 + el];
        float v0 = h2[(size_t)(p0.x & 0xFFFFF) * 16 + d] * __int_as_float(p0.y);
        float v1 = h2[(size_t)(p1.x & 0xFFFFF) * 16 + d] * __int_as_float(p1.y);
        float v2 = h2[(size_t)(p2.x & 0xFFFFF) * 16 + d] * __int_as_float(p2.y);
        float v3 = h2[(size_t)(p3.x & 0xFFFFF) * 16 + d] * __int_as_float(p3.y);
        atomicAdd(&agg[(p0.x >> 20) * 17 + d], v0);
        atomicAdd(&agg[(p1.x >> 20) * 17 + d], v1);
        atomicAdd(&agg[(p2.x >> 20) * 17 + d], v2);
        atomicAdd(&agg[(p3.x >> 20) * 17 + d], v3);
    }
    for (int e0 = full; e0 < count; e0 += 16) {
        int e = e0 + el;
        if (e < count) {
            int2 p = pk[e];
            float v = h2[(size_t)(p.x & 0xFFFFF) * 16 + d] * __int_as_float(p.y);
            atomicAdd(&agg[(p.x >> 20) * 17 + d], v);
        }
    }
    __syncthreads();
    int node0 = b * 256;
    for (int o = t; o < 256 * 16; o += 256) {
        int i = o >> 4, c = o & 15;
        int node = node0 + i;
        if (node < n)
            out[(size_t)node * 16 + c] = agg[i * 17 + c] * norm_dst[node] + sB2[c];
    }
}

extern "C" void kernel_launch(void* const* d_in, const int* in_sizes, int n_in,
                              void* d_out, int out_size, void* d_ws, size_t ws_size,
                              hipStream_t stream) {
    const float* feat = (const float*)d_in[0];
    const int*   src  = (const int*)d_in[1];
    const int*   dst  = (const int*)d_in[2];
    const float* ew   = (const float*)d_in[3];
    const float* W1   = (const float*)d_in[4];
    const float* b1   = (const float*)d_in[5];
    const float* W2   = (const float*)d_in[6];
    const float* b2   = (const float*)d_in[7];
    float* out = (float*)d_out;

    const int n = in_sizes[0] / 32;  // 100000
    const int m = in_sizes[1];       // 1600000

    // ws: pack[NB*CAPB int2] | h1[32n] | h2[16n] | norm_src[n] | norm_dst[n] |
    //     g_cur_d[NB] | g_cur_s[NB] | sp[NB*CAPB uchar]
    int2*  pack     = (int2*)d_ws;
    float* h1       = (float*)(pack + (size_t)NB * CAPB);
    float* h2       = h1 + 32 * (size_t)n;
    float* norm_src = h2 + 16 * (size_t)n;
    float* norm_dst = norm_src + n;
    int*   g_cur_d  = (int*)(norm_dst + n);
    int*   g_cur_s  = g_cur_d + NB;
    unsigned char* sp = (unsigned char*)(g_cur_s + NB);

    hipMemsetAsync(g_cur_d, 0, 2 * NB * sizeof(int), stream);  // bucket cursors

    partition_kernel<<<(m + EPB - 1) / EPB, 256, 0, stream>>>(src, dst, ew, g_cur_d, g_cur_s,
                                                              pack, sp, m);
    srcnorm_kernel<<<NB, 256, 0, stream>>>(sp, g_cur_s, norm_src, n);
    transform1_kernel<<<(n + 7) / 8, 256, 0, stream>>>(feat, norm_src, W1, h1, n);
    agg1_kernel<<<NB, 256, 0, stream>>>(h1, pack, g_cur_d, norm_src, W2, b1, h2, norm_dst, n);
    agg2_kernel<<<NB, 256, 0, stream>>>(h2, pack, g_cur_d, norm_dst, b2, out, n);
}

// Round 6
// 269.053 us; speedup vs baseline: 2.5484x; 2.5484x over previous
//
#include <hip/hip_runtime.h>
#include <hip/hip_fp16.h>

// GCN 2-layer. Round-4 structure (two-level partition -> LDS CSR -> per-node
// wave gathers) + fp16 hidden states (halved gather footprint) + 4-deep MLP.

#define NB   196      // buckets = ceil(100000/512); bucket = id >> 9
#define CAPB 10240    // padded per-bucket edge capacity
#define EPB  2048     // edges per partition block

// --- pass 1: partition edges by dst-bucket (int2 {src|dl<<20, w}) and
//     src ids by src-bucket (ushort src&511). Chunked, near-dense writes. ---
__global__ void partition_kernel(const int* __restrict__ src, const int* __restrict__ dst,
                                 const float* __restrict__ ew,
                                 int* __restrict__ g_cur_d, int* __restrict__ g_cur_s,
                                 int2* __restrict__ pack_part, unsigned short* __restrict__ src_part,
                                 int m) {
    __shared__ int hist_d[256], hist_s[256];
    __shared__ int cur_d[256], cur_s[256];
    int t = threadIdx.x;
    hist_d[t] = 0; hist_s[t] = 0;
    __syncthreads();
    int base_e = blockIdx.x * EPB;
    int es[8]; int ed[8]; float ewv[8];
#pragma unroll
    for (int k = 0; k < 8; k++) {
        int e = base_e + k * 256 + t;
        if (e < m) { es[k] = src[e]; ed[k] = dst[e]; ewv[k] = ew[e]; }
        else ed[k] = -1;
    }
#pragma unroll
    for (int k = 0; k < 8; k++) {
        if (ed[k] >= 0) {
            atomicAdd(&hist_d[ed[k] >> 9], 1);
            atomicAdd(&hist_s[es[k] >> 9], 1);
        }
    }
    __syncthreads();
    if (t < NB) {
        int c = hist_d[t];
        int b = c ? atomicAdd(&g_cur_d[t], c) : 0;
        cur_d[t] = t * CAPB + b;
        c = hist_s[t];
        b = c ? atomicAdd(&g_cur_s[t], c) : 0;
        cur_s[t] = t * CAPB + b;
    }
    __syncthreads();
#pragma unroll
    for (int k = 0; k < 8; k++) {
        if (ed[k] >= 0) {
            int d = ed[k];
            int pos = atomicAdd(&cur_d[d >> 9], 1);
            pack_part[pos] = make_int2(es[k] | ((d & 511) << 20), __float_as_int(ewv[k]));
            int sp = atomicAdd(&cur_s[es[k] >> 9], 1);
            src_part[sp] = (unsigned short)(es[k] & 511);
        }
    }
}

// --- per src-bucket: per-node out-degree in LDS -> norm_src ---
__global__ void srcnorm_kernel(const unsigned short* __restrict__ src_part,
                               const int* __restrict__ g_cur_s,
                               float* __restrict__ norm_src, int n) {
    __shared__ int cnt[512];
    int t = threadIdx.x, b = blockIdx.x;
    cnt[t] = 0;
    __syncthreads();
    int count = g_cur_s[b];
    const unsigned short* p = src_part + (size_t)b * CAPB;
    for (int e = t; e < count; e += 512) atomicAdd(&cnt[p[e]], 1);
    __syncthreads();
    int node = b * 512 + t;
    if (node < n) {
        int c = cnt[t];
        norm_src[node] = rsqrtf((float)(c > 1 ? c : 1));
    }
}

// --- per dst-bucket: exact CSR in LDS (hist + scan + scatter), stream out. ---
__global__ void csr_kernel(const int2* __restrict__ pack_part, const int* __restrict__ g_cur_d,
                           int2* __restrict__ csr, int* __restrict__ row_start,
                           int* __restrict__ cnt_dst, float* __restrict__ norm_dst, int n) {
    __shared__ int cnt[512];
    __shared__ int rowx[512];
    __shared__ int cur[512];
    extern __shared__ int2 stage[];  // CAPB entries
    int t = threadIdx.x, b = blockIdx.x;
    cnt[t] = 0; cur[t] = 0;
    __syncthreads();
    int count = g_cur_d[b];
    const int2* p = pack_part + (size_t)b * CAPB;
    for (int e = t; e < count; e += 512) atomicAdd(&cnt[p[e].x >> 20], 1);
    __syncthreads();
    int c0 = cnt[t];
    rowx[t] = c0;
    __syncthreads();
    for (int off = 1; off < 512; off <<= 1) {
        int v = (t >= off) ? rowx[t - off] : 0;
        __syncthreads();
        rowx[t] += v;
        __syncthreads();
    }
    int excl = rowx[t] - c0;
    __syncthreads();
    rowx[t] = excl;
    int node = b * 512 + t;
    if (node < n) {
        row_start[node] = b * CAPB + excl;
        cnt_dst[node] = c0;
        norm_dst[node] = rsqrtf((float)(c0 > 1 ? c0 : 1));
    }
    __syncthreads();
    for (int e = t; e < count; e += 512) {
        int2 v = p[e];
        int dl = v.x >> 20;
        int r = atomicAdd(&cur[dl], 1);
        stage[rowx[dl] + r] = make_int2(v.x & 0x1FFFF, v.y);
    }
    __syncthreads();
    int2* outp = csr + (size_t)b * CAPB;
    for (int e = t; e < count; e += 512) outp[e] = stage[e];
}

// --- h1[n,32] (fp16) = (feat * norm_src) @ W1 ---
__global__ void transform1_kernel(const float* __restrict__ feat,
                                  const float* __restrict__ norm_src,
                                  const float* __restrict__ W1,
                                  __half* __restrict__ h1, int n) {
    __shared__ float sW[32 * 32];
    __shared__ float sF[8][32];
    int t = threadIdx.x;
    for (int i = t; i < 32 * 32; i += 256) sW[i] = W1[i];
    int node0 = blockIdx.x * 8;
    int local = t >> 5, col = t & 31;
    int node = node0 + local;
    float f = 0.0f;
    if (node < n) f = feat[node * 32 + col] * norm_src[node];
    sF[local][col] = f;
    __syncthreads();
    if (node < n) {
        float acc = 0.0f;
#pragma unroll
        for (int k = 0; k < 32; k++) acc += sF[local][k] * sW[k * 32 + col];
        h1[(size_t)node * 32 + col] = __float2half(acc);
    }
}

// --- gather layer 1 + fused transform2: one wave/node, 2 phases x 32 dims,
//     4 edges in flight per phase ---
__global__ void gather1_fused_kernel(const __half* __restrict__ h1, const int2* __restrict__ csr,
                                     const int* __restrict__ row_start, const int* __restrict__ cnt,
                                     const float* __restrict__ norm_src, const float* __restrict__ norm_dst,
                                     const float* __restrict__ W2, const float* __restrict__ b1,
                                     __half* __restrict__ h2, int n) {
    __shared__ float sW2[32 * 16];
    __shared__ float sX[4][32];
    int t = threadIdx.x;
    for (int i = t; i < 32 * 16; i += 256) sW2[i] = W2[i];
    __syncthreads();
    int w = t >> 6;
    int lane = t & 63;
    int node = blockIdx.x * 4 + w;
    if (node >= n) return;
    int d = lane & 31;     // dim
    int eo = lane >> 5;    // edge phase 0/1
    long base = row_start[node];
    int c = cnt[node];
    float a0 = 0.0f, a1 = 0.0f, a2 = 0.0f, a3 = 0.0f;
    int j = eo;
    for (; j + 6 < c; j += 8) {  // 4 edges in flight per phase
        int2 p0 = csr[base + j];
        int2 p1 = csr[base + j + 2];
        int2 p2 = csr[base + j + 4];
        int2 p3 = csr[base + j + 6];
        a0 += __half2float(h1[(size_t)p0.x * 32 + d]) * __int_as_float(p0.y);
        a1 += __half2float(h1[(size_t)p1.x * 32 + d]) * __int_as_float(p1.y);
        a2 += __half2float(h1[(size_t)p2.x * 32 + d]) * __int_as_float(p2.y);
        a3 += __half2float(h1[(size_t)p3.x * 32 + d]) * __int_as_float(p3.y);
    }
    for (; j < c; j += 2) {
        int2 p = csr[base + j];
        a0 += __half2float(h1[(size_t)p.x * 32 + d]) * __int_as_float(p.y);
    }
    float acc = (a0 + a1) + (a2 + a3);
    acc += __shfl_xor(acc, 32);
    float x = acc * norm_dst[node] + b1[d];
    x = fmaxf(x, 0.0f) * norm_src[node];
    if (lane < 32) sX[w][d] = x;
    if (lane < 16) {
        float o = 0.0f;
#pragma unroll
        for (int k = 0; k < 32; k++) o += sX[w][k] * sW2[k * 16 + lane];
        h2[(size_t)node * 16 + lane] = __float2half(o);
    }
}

// --- gather layer 2 + fused epilogue: one wave/node, 4 phases x 16 dims,
//     4 edges in flight per phase ---
__global__ void gather2_kernel(const __half* __restrict__ h2, const int2* __restrict__ csr,
                               const int* __restrict__ row_start, const int* __restrict__ cnt,
                               const float* __restrict__ norm_dst, const float* __restrict__ b2,
                               float* __restrict__ out, int n) {
    int t = threadIdx.x;
    int w = t >> 6;
    int lane = t & 63;
    int node = blockIdx.x * 4 + w;
    if (node >= n) return;
    int d = lane & 15;   // dim
    int eo = lane >> 4;  // edge phase 0..3
    long base = row_start[node];
    int c = cnt[node];
    float a0 = 0.0f, a1 = 0.0f, a2 = 0.0f, a3 = 0.0f;
    int j = eo;
    for (; j + 12 < c; j += 16) {
        int2 p0 = csr[base + j];
        int2 p1 = csr[base + j + 4];
        int2 p2 = csr[base + j + 8];
        int2 p3 = csr[base + j + 12];
        a0 += __half2float(h2[(size_t)p0.x * 16 + d]) * __int_as_float(p0.y);
        a1 += __half2float(h2[(size_t)p1.x * 16 + d]) * __int_as_float(p1.y);
        a2 += __half2float(h2[(size_t)p2.x * 16 + d]) * __int_as_float(p2.y);
        a3 += __half2float(h2[(size_t)p3.x * 16 + d]) * __int_as_float(p3.y);
    }
    for (; j < c; j += 4) {
        int2 p = csr[base + j];
        a0 += __half2float(h2[(size_t)p.x * 16 + d]) * __int_as_float(p.y);
    }
    float acc = (a0 + a1) + (a2 + a3);
    acc += __shfl_xor(acc, 32);
    acc += __shfl_xor(acc, 16);
    if (lane < 16) out[(size_t)node * 16 + lane] = acc * norm_dst[node] + b2[lane];
}

extern "C" void kernel_launch(void* const* d_in, const int* in_sizes, int n_in,
                              void* d_out, int out_size, void* d_ws, size_t ws_size,
                              hipStream_t stream) {
    const float* feat = (const float*)d_in[0];
    const int*   src  = (const int*)d_in[1];
    const int*   dst  = (const int*)d_in[2];
    const float* ew   = (const float*)d_in[3];
    const float* W1   = (const float*)d_in[4];
    const float* b1   = (const float*)d_in[5];
    const float* W2   = (const float*)d_in[6];
    const float* b2   = (const float*)d_in[7];
    float* out = (float*)d_out;

    const int n = in_sizes[0] / 32;  // 100000
    const int m = in_sizes[1];       // 1600000

    // ws: pack_part[NB*CAPB int2] | csr[NB*CAPB int2] | h1 half[32n] | h2 half[16n] |
    //     norm_src[n] | norm_dst[n] | row_start[n] | cnt_dst[n] |
    //     g_cur_d[NB] | g_cur_s[NB] | src_part[NB*CAPB ushort]
    char* wsb = (char*)d_ws;
    int2*   pack_part = (int2*)wsb;
    int2*   csr       = pack_part + (size_t)NB * CAPB;
    __half* h1        = (__half*)(csr + (size_t)NB * CAPB);
    __half* h2        = h1 + 32 * (size_t)n;
    float*  norm_src  = (float*)(h2 + 16 * (size_t)n);
    float*  norm_dst  = norm_src + n;
    int*    row_start = (int*)(norm_dst + n);
    int*    cnt_dst   = row_start + n;
    int*    g_cur_d   = cnt_dst + n;
    int*    g_cur_s   = g_cur_d + NB;
    unsigned short* src_part = (unsigned short*)(g_cur_s + NB);

    hipMemsetAsync(g_cur_d, 0, 2 * NB * sizeof(int), stream);

    partition_kernel<<<(m + EPB - 1) / EPB, 256, 0, stream>>>(src, dst, ew, g_cur_d, g_cur_s,
                                                              pack_part, src_part, m);
    srcnorm_kernel<<<NB, 512, 0, stream>>>(src_part, g_cur_s, norm_src, n);
    csr_kernel<<<NB, 512, CAPB * sizeof(int2), stream>>>(pack_part, g_cur_d, csr,
                                                         row_start, cnt_dst, norm_dst, n);
    transform1_kernel<<<(n + 7) / 8, 256, 0, stream>>>(feat, norm_src, W1, h1, n);
    gather1_fused_kernel<<<(n + 3) / 4, 256, 0, stream>>>(h1, csr, row_start, cnt_dst,
                                                          norm_src, norm_dst, W2, b1, h2, n);
    gather2_kernel<<<(n + 3) / 4, 256, 0, stream>>>(h2, csr, row_start, cnt_dst,
                                                    norm_dst, b2, out, n);
}

// Round 7
// 234.019 us; speedup vs baseline: 2.9299x; 1.1497x over previous
//
#include <hip/hip_runtime.h>
#include <hip/hip_fp16.h>

// GCN 2-layer. Two-level partition -> LDS CSR -> per-node wave gathers.
// fp16 hidden states; half2 lanes => 4 (resp. 8) edge phases per wave for
// max lines-in-flight on the random h reads.

#define NB   196      // buckets = ceil(100000/512); bucket = id >> 9
#define CAPB 10240    // padded per-bucket edge capacity
#define EPB  4096     // edges per partition block (16/thread)

// --- pass 1: partition edges by dst-bucket (int2 {src|dl<<20, w}) and
//     src ids by src-bucket (ushort src&511). Chunked, near-dense writes. ---
__global__ void partition_kernel(const int* __restrict__ src, const int* __restrict__ dst,
                                 const float* __restrict__ ew,
                                 int* __restrict__ g_cur_d, int* __restrict__ g_cur_s,
                                 int2* __restrict__ pack_part, unsigned short* __restrict__ src_part,
                                 int m) {
    __shared__ int hist_d[256], hist_s[256];
    __shared__ int cur_d[256], cur_s[256];
    int t = threadIdx.x;
    hist_d[t] = 0; hist_s[t] = 0;
    __syncthreads();
    int base_e = blockIdx.x * EPB;
    int es[16]; int ed[16]; float ewv[16];
#pragma unroll
    for (int k = 0; k < 16; k++) {
        int e = base_e + k * 256 + t;
        if (e < m) { es[k] = src[e]; ed[k] = dst[e]; ewv[k] = ew[e]; }
        else ed[k] = -1;
    }
#pragma unroll
    for (int k = 0; k < 16; k++) {
        if (ed[k] >= 0) {
            atomicAdd(&hist_d[ed[k] >> 9], 1);
            atomicAdd(&hist_s[es[k] >> 9], 1);
        }
    }
    __syncthreads();
    if (t < NB) {
        int c = hist_d[t];
        int b = c ? atomicAdd(&g_cur_d[t], c) : 0;
        cur_d[t] = t * CAPB + b;
        c = hist_s[t];
        b = c ? atomicAdd(&g_cur_s[t], c) : 0;
        cur_s[t] = t * CAPB + b;
    }
    __syncthreads();
#pragma unroll
    for (int k = 0; k < 16; k++) {
        if (ed[k] >= 0) {
            int d = ed[k];
            int pos = atomicAdd(&cur_d[d >> 9], 1);
            pack_part[pos] = make_int2(es[k] | ((d & 511) << 20), __float_as_int(ewv[k]));
            int sp = atomicAdd(&cur_s[es[k] >> 9], 1);
            src_part[sp] = (unsigned short)(es[k] & 511);
        }
    }
}

// --- per src-bucket: per-node out-degree in LDS -> norm_src ---
__global__ void srcnorm_kernel(const unsigned short* __restrict__ src_part,
                               const int* __restrict__ g_cur_s,
                               float* __restrict__ norm_src, int n) {
    __shared__ int cnt[512];
    int t = threadIdx.x, b = blockIdx.x;
    cnt[t] = 0;
    __syncthreads();
    int count = g_cur_s[b];
    const unsigned short* p = src_part + (size_t)b * CAPB;
    for (int e = t; e < count; e += 512) atomicAdd(&cnt[p[e]], 1);
    __syncthreads();
    int node = b * 512 + t;
    if (node < n) {
        int c = cnt[t];
        norm_src[node] = rsqrtf((float)(c > 1 ? c : 1));
    }
}

// --- per dst-bucket: exact CSR in LDS (hist + scan + scatter), stream out. ---
__global__ void csr_kernel(const int2* __restrict__ pack_part, const int* __restrict__ g_cur_d,
                           int2* __restrict__ csr, int* __restrict__ row_start,
                           int* __restrict__ cnt_dst, float* __restrict__ norm_dst, int n) {
    __shared__ int cnt[512];
    __shared__ int rowx[512];
    __shared__ int cur[512];
    extern __shared__ int2 stage[];  // CAPB entries
    int t = threadIdx.x, b = blockIdx.x;
    cnt[t] = 0; cur[t] = 0;
    __syncthreads();
    int count = g_cur_d[b];
    const int2* p = pack_part + (size_t)b * CAPB;
    for (int e = t; e < count; e += 512) atomicAdd(&cnt[p[e].x >> 20], 1);
    __syncthreads();
    int c0 = cnt[t];
    rowx[t] = c0;
    __syncthreads();
    for (int off = 1; off < 512; off <<= 1) {
        int v = (t >= off) ? rowx[t - off] : 0;
        __syncthreads();
        rowx[t] += v;
        __syncthreads();
    }
    int excl = rowx[t] - c0;
    __syncthreads();
    rowx[t] = excl;
    int node = b * 512 + t;
    if (node < n) {
        row_start[node] = b * CAPB + excl;
        cnt_dst[node] = c0;
        norm_dst[node] = rsqrtf((float)(c0 > 1 ? c0 : 1));
    }
    __syncthreads();
    for (int e = t; e < count; e += 512) {
        int2 v = p[e];
        int dl = v.x >> 20;
        int r = atomicAdd(&cur[dl], 1);
        stage[rowx[dl] + r] = make_int2(v.x & 0x1FFFF, v.y);
    }
    __syncthreads();
    int2* outp = csr + (size_t)b * CAPB;
    for (int e = t; e < count; e += 512) outp[e] = stage[e];
}

// --- h1[n,32] (fp16) = (feat * norm_src) @ W1 ---
__global__ void transform1_kernel(const float* __restrict__ feat,
                                  const float* __restrict__ norm_src,
                                  const float* __restrict__ W1,
                                  __half* __restrict__ h1, int n) {
    __shared__ float sW[32 * 32];
    __shared__ float sF[8][32];
    int t = threadIdx.x;
    for (int i = t; i < 32 * 32; i += 256) sW[i] = W1[i];
    int node0 = blockIdx.x * 8;
    int local = t >> 5, col = t & 31;
    int node = node0 + local;
    float f = 0.0f;
    if (node < n) f = feat[node * 32 + col] * norm_src[node];
    sF[local][col] = f;
    __syncthreads();
    if (node < n) {
        float acc = 0.0f;
#pragma unroll
        for (int k = 0; k < 32; k++) acc += sF[local][k] * sW[k * 32 + col];
        h1[(size_t)node * 32 + col] = __float2half(acc);
    }
}

// --- gather layer 1 + fused transform2: one wave/node, half2 lanes,
//     4 edge phases x 4-deep unroll = 16 rows in flight ---
__global__ void gather1_fused_kernel(const __half* __restrict__ h1, const int2* __restrict__ csr,
                                     const int* __restrict__ row_start, const int* __restrict__ cnt,
                                     const float* __restrict__ norm_src, const float* __restrict__ norm_dst,
                                     const float* __restrict__ W2, const float* __restrict__ b1,
                                     __half* __restrict__ h2, int n) {
    __shared__ float sW2[32 * 16];
    __shared__ float sX[4][32];
    int t = threadIdx.x;
    for (int i = t; i < 32 * 16; i += 256) sW2[i] = W2[i];
    __syncthreads();
    int w = t >> 6;
    int lane = t & 63;
    int node = blockIdx.x * 4 + w;
    if (node >= n) return;
    int dh = lane & 15;    // half2 index within row (dims 2*dh, 2*dh+1)
    int eo = lane >> 4;    // edge phase 0..3
    long base = row_start[node];
    int c = cnt[node];
    const __half2* h1v = (const __half2*)h1;   // rows of 16 half2
    float ax0 = 0.f, ay0 = 0.f, ax1 = 0.f, ay1 = 0.f;
    float ax2 = 0.f, ay2 = 0.f, ax3 = 0.f, ay3 = 0.f;
    int j = eo;
    for (; j + 12 < c; j += 16) {   // 4 rows in flight per phase
        int2 p0 = csr[base + j];
        int2 p1 = csr[base + j + 4];
        int2 p2 = csr[base + j + 8];
        int2 p3 = csr[base + j + 12];
        float2 v0 = __half22float2(h1v[(size_t)p0.x * 16 + dh]);
        float2 v1 = __half22float2(h1v[(size_t)p1.x * 16 + dh]);
        float2 v2 = __half22float2(h1v[(size_t)p2.x * 16 + dh]);
        float2 v3 = __half22float2(h1v[(size_t)p3.x * 16 + dh]);
        float w0 = __int_as_float(p0.y), w1 = __int_as_float(p1.y);
        float w2 = __int_as_float(p2.y), w3 = __int_as_float(p3.y);
        ax0 += v0.x * w0; ay0 += v0.y * w0;
        ax1 += v1.x * w1; ay1 += v1.y * w1;
        ax2 += v2.x * w2; ay2 += v2.y * w2;
        ax3 += v3.x * w3; ay3 += v3.y * w3;
    }
    for (; j < c; j += 4) {
        int2 p = csr[base + j];
        float2 v = __half22float2(h1v[(size_t)p.x * 16 + dh]);
        float ww = __int_as_float(p.y);
        ax0 += v.x * ww; ay0 += v.y * ww;
    }
    float ax = (ax0 + ax1) + (ax2 + ax3);
    float ay = (ay0 + ay1) + (ay2 + ay3);
    ax += __shfl_xor(ax, 16); ay += __shfl_xor(ay, 16);
    ax += __shfl_xor(ax, 32); ay += __shfl_xor(ay, 32);
    if (lane < 16) {
        float nd = norm_dst[node], ns = norm_src[node];
        float x0 = fmaxf(ax * nd + b1[2 * dh],     0.0f) * ns;
        float x1 = fmaxf(ay * nd + b1[2 * dh + 1], 0.0f) * ns;
        sX[w][2 * dh]     = x0;
        sX[w][2 * dh + 1] = x1;
    }
    // wave-synchronous: lanes<16 wrote sX, lanes<16 read it
    if (lane < 16) {
        float o = 0.0f;
#pragma unroll
        for (int k = 0; k < 32; k++) o += sX[w][k] * sW2[k * 16 + lane];
        h2[(size_t)node * 16 + lane] = __float2half(o);
    }
}

// --- gather layer 2 + fused epilogue: one wave/node, half2 lanes,
//     8 edge phases x 2-deep unroll ---
__global__ void gather2_kernel(const __half* __restrict__ h2, const int2* __restrict__ csr,
                               const int* __restrict__ row_start, const int* __restrict__ cnt,
                               const float* __restrict__ norm_dst, const float* __restrict__ b2,
                               float* __restrict__ out, int n) {
    int t = threadIdx.x;
    int w = t >> 6;
    int lane = t & 63;
    int node = blockIdx.x * 4 + w;
    if (node >= n) return;
    int dh = lane & 7;    // half2 index within row (dims 2*dh, 2*dh+1)
    int eo = lane >> 3;   // edge phase 0..7
    long base = row_start[node];
    int c = cnt[node];
    const __half2* h2v = (const __half2*)h2;   // rows of 8 half2
    float ax0 = 0.f, ay0 = 0.f, ax1 = 0.f, ay1 = 0.f;
    int j = eo;
    for (; j + 8 < c; j += 16) {
        int2 p0 = csr[base + j];
        int2 p1 = csr[base + j + 8];
        float2 v0 = __half22float2(h2v[(size_t)p0.x * 8 + dh]);
        float2 v1 = __half22float2(h2v[(size_t)p1.x * 8 + dh]);
        float w0 = __int_as_float(p0.y), w1 = __int_as_float(p1.y);
        ax0 += v0.x * w0; ay0 += v0.y * w0;
        ax1 += v1.x * w1; ay1 += v1.y * w1;
    }
    for (; j < c; j += 8) {
        int2 p = csr[base + j];
        float2 v = __half22float2(h2v[(size_t)p.x * 8 + dh]);
        float ww = __int_as_float(p.y);
        ax0 += v.x * ww; ay0 += v.y * ww;
    }
    float ax = ax0 + ax1, ay = ay0 + ay1;
    ax += __shfl_xor(ax, 8);  ay += __shfl_xor(ay, 8);
    ax += __shfl_xor(ax, 16); ay += __shfl_xor(ay, 16);
    ax += __shfl_xor(ax, 32); ay += __shfl_xor(ay, 32);
    if (lane < 8) {
        float nd = norm_dst[node];
        float2 o;
        o.x = ax * nd + b2[2 * dh];
        o.y = ay * nd + b2[2 * dh + 1];
        ((float2*)out)[(size_t)node * 8 + dh] = o;
    }
}

extern "C" void kernel_launch(void* const* d_in, const int* in_sizes, int n_in,
                              void* d_out, int out_size, void* d_ws, size_t ws_size,
                              hipStream_t stream) {
    const float* feat = (const float*)d_in[0];
    const int*   src  = (const int*)d_in[1];
    const int*   dst  = (const int*)d_in[2];
    const float* ew   = (const float*)d_in[3];
    const float* W1   = (const float*)d_in[4];
    const float* b1   = (const float*)d_in[5];
    const float* W2   = (const float*)d_in[6];
    const float* b2   = (const float*)d_in[7];
    float* out = (float*)d_out;

    const int n = in_sizes[0] / 32;  // 100000
    const int m = in_sizes[1];       // 1600000

    // ws: pack_part[NB*CAPB int2] | csr[NB*CAPB int2] | h1 half[32n] | h2 half[16n] |
    //     norm_src[n] | norm_dst[n] | row_start[n] | cnt_dst[n] |
    //     g_cur_d[NB] | g_cur_s[NB] | src_part[NB*CAPB ushort]
    char* wsb = (char*)d_ws;
    int2*   pack_part = (int2*)wsb;
    int2*   csr       = pack_part + (size_t)NB * CAPB;
    __half* h1        = (__half*)(csr + (size_t)NB * CAPB);
    __half* h2        = h1 + 32 * (size_t)n;
    float*  norm_src  = (float*)(h2 + 16 * (size_t)n);
    float*  norm_dst  = norm_src + n;
    int*    row_start = (int*)(norm_dst + n);
    int*    cnt_dst   = row_start + n;
    int*    g_cur_d   = cnt_dst + n;
    int*    g_cur_s   = g_cur_d + NB;
    unsigned short* src_part = (unsigned short*)(g_cur_s + NB);

    hipMemsetAsync(g_cur_d, 0, 2 * NB * sizeof(int), stream);

    partition_kernel<<<(m + EPB - 1) / EPB, 256, 0, stream>>>(src, dst, ew, g_cur_d, g_cur_s,
                                                              pack_part, src_part, m);
    srcnorm_kernel<<<NB, 512, 0, stream>>>(src_part, g_cur_s, norm_src, n);
    csr_kernel<<<NB, 512, CAPB * sizeof(int2), stream>>>(pack_part, g_cur_d, csr,
                                                         row_start, cnt_dst, norm_dst, n);
    transform1_kernel<<<(n + 7) / 8, 256, 0, stream>>>(feat, norm_src, W1, h1, n);
    gather1_fused_kernel<<<(n + 3) / 4, 256, 0, stream>>>(h1, csr, row_start, cnt_dst,
                                                          norm_src, norm_dst, W2, b1, h2, n);
    gather2_kernel<<<(n + 3) / 4, 256, 0, stream>>>(h2, csr, row_start, cnt_dst,
                                                    norm_dst, b2, out, n);
}